// Round 1
// baseline (1411.276 us; speedup 1.0000x reference)
//
#include <hip/hip_runtime.h>
#include <cmath>

// Problem constants (from reference): x [B=4096][T=512][D=4], H=32, gates 4H=128.
constexpr int T  = 512;
constexpr int D  = 4;
constexpr int H  = 32;
constexpr int G4 = 128;   // 4*H
constexpr int BLK = 256;  // threads per block: 128 L1 gate-threads + 128 L2 gate-threads

// Fused 2-layer LSTM, one block per batch element, wave-specialized pipeline:
//   threads [0,128)   -> layer-1 gate rows r=tid   (weights in VGPRs)
//   threads [128,256) -> layer-2 gate rows r=tid-128
// Iteration i: L1 computes timestep t=i (i<T); L2 computes t=i-1 (i>=1).
// Both read h0_s (layer-1 hidden from previous phase-B). 2 barriers/iter.
__global__ __launch_bounds__(BLK) void lstm_fused(
    const float* __restrict__ x,
    const float* __restrict__ W_ih0, const float* __restrict__ W_hh0,
    const float* __restrict__ b_ih0, const float* __restrict__ b_hh0,
    const float* __restrict__ W_ih1, const float* __restrict__ W_hh1,
    const float* __restrict__ b_ih1, const float* __restrict__ b_hh1,
    const float* __restrict__ W_out, const float* __restrict__ b_out,
    float* __restrict__ out)
{
    __shared__ __align__(16) float x_s[T * D];   // 8 KB: this batch row of x
    __shared__ __align__(16) float h0_s[H];      // layer-1 hidden
    __shared__ __align__(16) float h1_s[H];      // layer-2 hidden
    __shared__ __align__(16) float g0_s[G4];     // layer-1 activated gates
    __shared__ __align__(16) float g1_s[G4];     // layer-2 activated gates

    const int tid = threadIdx.x;
    const int b   = blockIdx.x;

    // ---- preload x[b] (contiguous 8 KB, coalesced float4) ----
    const float4* xb = (const float4*)(x + (size_t)b * (T * D));
    #pragma unroll
    for (int idx = tid; idx < T; idx += BLK) {
        ((float4*)x_s)[idx] = xb[idx];
    }

    // ---- load weights into registers ----
    const bool isL1 = (tid < G4);
    const int  r    = tid & (G4 - 1);
    float wA[H];   // L1: W_hh0 row r   | L2: W_ih1 row r   (dotted with h0_s)
    float wB[H];   // L1: W_ih0 row r (first 4) | L2: W_hh1 row r (dotted with h1_s)
    float bias;
    {
        const float* WA = isL1 ? (W_hh0 + r * H) : (W_ih1 + r * H);
        #pragma unroll
        for (int kk = 0; kk < H / 4; ++kk) {
            float4 v = ((const float4*)WA)[kk];
            wA[4*kk+0] = v.x; wA[4*kk+1] = v.y; wA[4*kk+2] = v.z; wA[4*kk+3] = v.w;
        }
        if (isL1) {
            float4 v = *((const float4*)(W_ih0 + r * D));
            wB[0] = v.x; wB[1] = v.y; wB[2] = v.z; wB[3] = v.w;
            #pragma unroll
            for (int k = 4; k < H; ++k) wB[k] = 0.0f;
            bias = b_ih0[r] + b_hh0[r];
        } else {
            const float* WB = W_hh1 + r * H;
            #pragma unroll
            for (int kk = 0; kk < H / 4; ++kk) {
                float4 v = ((const float4*)WB)[kk];
                wB[4*kk+0] = v.x; wB[4*kk+1] = v.y; wB[4*kk+2] = v.z; wB[4*kk+3] = v.w;
            }
            bias = b_ih1[r] + b_hh1[r];
        }
    }

    // ---- init states ----
    if (tid < H) h0_s[tid] = 0.0f;
    if (tid >= G4 && tid < G4 + H) h1_s[tid - G4] = 0.0f;
    float c = 0.0f;  // c0 for tid<32 ; c1 for tid in [128,160)

    __syncthreads();

    const int  gidx      = r >> 5;          // 0:i 1:f 2:g 3:o  (PyTorch order)
    const bool gate_tanh = (gidx == 2);

    for (int i = 0; i <= T; ++i) {
        // ---------- phase A: gate rows ----------
        const bool active = isL1 ? (i < T) : (i >= 1);
        if (active) {
            float acc0 = bias, acc1 = 0.0f, acc2 = 0.0f, acc3 = 0.0f;
            #pragma unroll
            for (int kk = 0; kk < H / 4; ++kk) {      // dot(h0, wA) — both layers
                float4 h4 = ((const float4*)h0_s)[kk];
                acc0 = fmaf(h4.x, wA[4*kk+0], acc0);
                acc1 = fmaf(h4.y, wA[4*kk+1], acc1);
                acc2 = fmaf(h4.z, wA[4*kk+2], acc2);
                acc3 = fmaf(h4.w, wA[4*kk+3], acc3);
            }
            if (isL1) {                               // + dot(x[t], W_ih0 row)
                float4 xv = ((const float4*)x_s)[i];
                acc0 = fmaf(xv.x, wB[0], acc0);
                acc1 = fmaf(xv.y, wB[1], acc1);
                acc2 = fmaf(xv.z, wB[2], acc2);
                acc3 = fmaf(xv.w, wB[3], acc3);
            } else {                                  // + dot(h1, W_hh1 row)
                #pragma unroll
                for (int kk = 0; kk < H / 4; ++kk) {
                    float4 h4 = ((const float4*)h1_s)[kk];
                    acc0 = fmaf(h4.x, wB[4*kk+0], acc0);
                    acc1 = fmaf(h4.y, wB[4*kk+1], acc1);
                    acc2 = fmaf(h4.z, wB[4*kk+2], acc2);
                    acc3 = fmaf(h4.w, wB[4*kk+3], acc3);
                }
            }
            float acc = (acc0 + acc1) + (acc2 + acc3);
            // activation: sigmoid for i,f,o ; tanh for g (tanh(a) = 2*sigmoid(2a)-1)
            float s = 1.0f / (1.0f + expf(gate_tanh ? (-2.0f * acc) : (-acc)));
            float a = gate_tanh ? (2.0f * s - 1.0f) : s;
            (isL1 ? g0_s : g1_s)[r] = a;
        }
        __syncthreads();

        // ---------- phase B: state update (units 0..31 of each half) ----------
        if (isL1) {
            if (tid < H && i < T) {
                float ig = g0_s[tid], fg = g0_s[tid + H];
                float gg = g0_s[tid + 2*H], og = g0_s[tid + 3*H];
                c = fmaf(fg, c, ig * gg);
                h0_s[tid] = og * tanhf(c);
            }
        } else {
            int j = tid - G4;
            if (j < H && i >= 1) {
                float ig = g1_s[j], fg = g1_s[j + H];
                float gg = g1_s[j + 2*H], og = g1_s[j + 3*H];
                c = fmaf(fg, c, ig * gg);
                h1_s[j] = og * tanhf(c);
            }
        }
        __syncthreads();
    }

    // ---- output head: out[b] = b_out + W_out · h1(T-1) ----
    if (tid == 0) {
        float acc = b_out[0];
        #pragma unroll
        for (int j = 0; j < H; ++j) acc = fmaf(W_out[j], h1_s[j], acc);
        out[b] = acc;
    }
}

extern "C" void kernel_launch(void* const* d_in, const int* in_sizes, int n_in,
                              void* d_out, int out_size, void* d_ws, size_t ws_size,
                              hipStream_t stream) {
    const float* x     = (const float*)d_in[0];
    const float* W_ih0 = (const float*)d_in[1];
    const float* W_hh0 = (const float*)d_in[2];
    const float* b_ih0 = (const float*)d_in[3];
    const float* b_hh0 = (const float*)d_in[4];
    const float* W_ih1 = (const float*)d_in[5];
    const float* W_hh1 = (const float*)d_in[6];
    const float* b_ih1 = (const float*)d_in[7];
    const float* b_hh1 = (const float*)d_in[8];
    const float* W_out = (const float*)d_in[9];
    const float* b_out = (const float*)d_in[10];
    float* out = (float*)d_out;

    const int B = 4096;  // out_size == 4096 == batch
    lstm_fused<<<B, BLK, 0, stream>>>(x, W_ih0, W_hh0, b_ih0, b_hh0,
                                      W_ih1, W_hh1, b_ih1, b_hh1,
                                      W_out, b_out, out);
}

// Round 2
// 1332.162 us; speedup vs baseline: 1.0594x; 1.0594x over previous
//
#include <hip/hip_runtime.h>
#include <cmath>

// x [B=4096][T=512][D=4], H=32, 4H=128 gate rows per layer.
constexpr int T   = 512;
constexpr int D   = 4;
constexpr int H   = 32;
constexpr int BLK = 128;   // wave0 = layer1, wave1 = layer2; one block per batch elem

typedef float v2f __attribute__((ext_vector_type(2)));

static __device__ __forceinline__ v2f mk2(float a, float b) {
    v2f r; r.x = a; r.y = b; return r;
}

// One block per batch element. Lane l of each layer-wave owns gate rows l and
// l+64 (so lanes<32 hold {i,g} of unit l, lanes>=32 hold {f,o} of unit l-32;
// the f/o values reach the state-updating lanes via __shfl_xor(32) — no LDS
// round trip for gates). h vectors are double-buffered in LDS => ONE barrier
// per timestep. Pipeline skew: at iter i, L1 computes step i, L2 computes
// step i-1; both consume h0(i-1) from buffer (i&1).
__global__ __launch_bounds__(BLK) void lstm_fused(
    const float* __restrict__ x,
    const float* __restrict__ W_ih0, const float* __restrict__ W_hh0,
    const float* __restrict__ b_ih0, const float* __restrict__ b_hh0,
    const float* __restrict__ W_ih1, const float* __restrict__ W_hh1,
    const float* __restrict__ b_ih1, const float* __restrict__ b_hh1,
    const float* __restrict__ W_out, const float* __restrict__ b_out,
    float* __restrict__ out)
{
    __shared__ __align__(16) float x_s[T * D];      // 8 KB
    __shared__ __align__(16) float h0_s[2][H];      // double-buffered hidden, L1
    __shared__ __align__(16) float h1_s[2][H];      // double-buffered hidden, L2

    const int tid = threadIdx.x;
    const int b   = blockIdx.x;

    // preload x[b] (contiguous, coalesced float4)
    const float4* xb = (const float4*)(x + (size_t)b * (T * D));
    #pragma unroll 4
    for (int idx = tid; idx < T; idx += BLK) ((float4*)x_s)[idx] = xb[idx];
    if (tid < 2 * H) {
        h0_s[tid >> 5][tid & 31] = 0.0f;
        h1_s[tid >> 5][tid & 31] = 0.0f;
    }

    const int wave = tid >> 6;       // 0 = layer1, 1 = layer2
    const int lane = tid & 63;
    const int rA = lane, rB = lane + 64;

    // weights, packed as {row rA, row rB} pairs so FMAs become v_pk_fma_f32
    v2f w0[H];        // dotted with h0: wave0 -> W_hh0 ; wave1 -> W_ih1
    v2f w1[H];        // wave1 only: dotted with h1 (W_hh1)
    v2f wx[D];        // wave0 only: W_ih0 (dotted with x[t])
    v2f bias;

    if (wave == 0) {
        #pragma unroll
        for (int k = 0; k < H; ++k) w0[k] = mk2(W_hh0[rA*H + k], W_hh0[rB*H + k]);
        #pragma unroll
        for (int k = 0; k < D; ++k) wx[k] = mk2(W_ih0[rA*D + k], W_ih0[rB*D + k]);
        bias = mk2(b_ih0[rA] + b_hh0[rA], b_ih0[rB] + b_hh0[rB]);
    } else {
        #pragma unroll
        for (int k = 0; k < H; ++k) w0[k] = mk2(W_ih1[rA*H + k], W_ih1[rB*H + k]);
        #pragma unroll
        for (int k = 0; k < H; ++k) w1[k] = mk2(W_hh1[rA*H + k], W_hh1[rB*H + k]);
        bias = mk2(b_ih1[rA] + b_hh1[rA], b_ih1[rB] + b_hh1[rB]);
    }

    // activation of the second row (rB): lanes<32 -> g-gate (tanh), else o (sigmoid)
    // tanh(z) = 2*sigmoid(2z) - 1  => uniform code via per-lane constants
    const float s1  = (lane < H) ? 2.0f : 1.0f;
    const float off = (lane < H) ? 1.0f : 0.0f;

    float c = 0.0f;   // cell state, lives in lanes<32 of each wave

    __syncthreads();

    for (int i = 0; i <= T; ++i) {
        const int rb = i & 1, wb = rb ^ 1;

        v2f acc0 = bias, acc1 = mk2(0,0), acc2 = mk2(0,0), acc3 = mk2(0,0);
        const float4* h0p = (const float4*)h0_s[rb];
        #pragma unroll
        for (int kk = 0; kk < H/4; ++kk) {           // dot(h0, w0) — both waves
            float4 h4 = h0p[kk];
            acc0 += h4.x * w0[4*kk+0];
            acc1 += h4.y * w0[4*kk+1];
            acc2 += h4.z * w0[4*kk+2];
            acc3 += h4.w * w0[4*kk+3];
        }
        if (wave == 0) {                             // + dot(x[t], W_ih0)
            float4 xv = ((const float4*)x_s)[(i < T) ? i : (T - 1)];
            acc0 += xv.x * wx[0];
            acc1 += xv.y * wx[1];
            acc2 += xv.z * wx[2];
            acc3 += xv.w * wx[3];
        } else {                                     // + dot(h1, W_hh1)
            const float4* h1p = (const float4*)h1_s[rb];
            #pragma unroll
            for (int kk = 0; kk < H/4; ++kk) {
                float4 h4 = h1p[kk];
                acc0 += h4.x * w1[4*kk+0];
                acc1 += h4.y * w1[4*kk+1];
                acc2 += h4.z * w1[4*kk+2];
                acc3 += h4.w * w1[4*kk+3];
            }
        }
        v2f g2 = (acc0 + acc1) + (acc2 + acc3);      // g2.x: row rA, g2.y: row rB

        // a0 = sigmoid(g2.x)  (i for lanes<32, f for lanes>=32)
        float a0 = __builtin_amdgcn_rcpf(1.0f + __expf(-g2.x));
        // a1 = lanes<32 ? tanh(g2.y) : sigmoid(g2.y)
        float sg = __builtin_amdgcn_rcpf(1.0f + __expf(-g2.y * s1));
        float a1 = fmaf(sg, s1, -off);

        // lanes<32 fetch f,o from lanes+32 (same wave — no barrier needed)
        float f_ = __shfl_xor(a0, 32);
        float o_ = __shfl_xor(a1, 32);

        const bool active = (wave == 0) ? (i < T) : (i >= 1);
        if (lane < H && active) {
            c = fmaf(f_, c, a0 * a1);                        // c = f*c + i*g
            float th = fmaf(__builtin_amdgcn_rcpf(1.0f + __expf(-2.0f * c)), 2.0f, -1.0f);
            float hv = o_ * th;                              // h = o * tanh(c)
            (wave == 0 ? h0_s : h1_s)[wb][lane] = hv;
        }
        __syncthreads();   // single barrier: writes to buf wb visible, reads of buf rb done
    }

    // final h1 = h1(T-1), written at iter i=T into buffer (T&1)^1 = 1
    if (tid == 0) {
        float acc = b_out[0];
        const float* hf = h1_s[(T & 1) ^ 1];
        #pragma unroll
        for (int j = 0; j < H; ++j) acc = fmaf(W_out[j], hf[j], acc);
        out[b] = acc;
    }
}

extern "C" void kernel_launch(void* const* d_in, const int* in_sizes, int n_in,
                              void* d_out, int out_size, void* d_ws, size_t ws_size,
                              hipStream_t stream) {
    const float* x     = (const float*)d_in[0];
    const float* W_ih0 = (const float*)d_in[1];
    const float* W_hh0 = (const float*)d_in[2];
    const float* b_ih0 = (const float*)d_in[3];
    const float* b_hh0 = (const float*)d_in[4];
    const float* W_ih1 = (const float*)d_in[5];
    const float* W_hh1 = (const float*)d_in[6];
    const float* b_ih1 = (const float*)d_in[7];
    const float* b_hh1 = (const float*)d_in[8];
    const float* W_out = (const float*)d_in[9];
    const float* b_out = (const float*)d_in[10];
    float* out = (float*)d_out;

    const int B = out_size;   // 4096
    lstm_fused<<<B, BLK, 0, stream>>>(x, W_ih0, W_hh0, b_ih0, b_hh0,
                                      W_ih1, W_hh1, b_ih1, b_hh1,
                                      W_out, b_out, out);
}

// Round 3
// 1191.376 us; speedup vs baseline: 1.1846x; 1.1182x over previous
//
#include <hip/hip_runtime.h>
#include <cmath>

// x [B=4096][T=512][D=4], H=32, 4H=128 gate rows per layer.
constexpr int T   = 512;
constexpr int D   = 4;
constexpr int H   = 32;
constexpr int BLK = 64;   // ONE wave per batch element; both layers in-wave; no barriers

typedef float v2f __attribute__((ext_vector_type(2)));

static __device__ __forceinline__ v2f mk2(float a, float b) {
    v2f r; r.x = a; r.y = b; return r;
}

// Lane l owns gate rows (l, l+64) of BOTH layers:
//   l<32 : rowA = i-gate[l],    rowB = g-gate[l]     (tanh on rowB)
//   l>=32: rowA = f-gate[l-32], rowB = o-gate[l-32]
// f,o reach the state-updating lanes (<32) via __shfl_xor(32). h0/h1 are
// broadcast through LDS; single-wave blocks mean write->read needs only
// lgkmcnt ordering (compiler-inserted), never s_barrier.
__global__ __launch_bounds__(BLK, 2) void lstm_fused(
    const float* __restrict__ x,
    const float* __restrict__ W_ih0, const float* __restrict__ W_hh0,
    const float* __restrict__ b_ih0, const float* __restrict__ b_hh0,
    const float* __restrict__ W_ih1, const float* __restrict__ W_hh1,
    const float* __restrict__ b_ih1, const float* __restrict__ b_hh1,
    const float* __restrict__ W_out, const float* __restrict__ b_out,
    float* __restrict__ out)
{
    __shared__ __align__(16) float x_s[T * D];   // 8 KB
    __shared__ __align__(16) float h0_s[H];
    __shared__ __align__(16) float h1_s[H];

    const int lane = threadIdx.x;   // 0..63
    const int b    = blockIdx.x;

    // preload x[b] (contiguous, coalesced float4: 8 per lane)
    const float4* xb = (const float4*)(x + (size_t)b * (T * D));
    #pragma unroll
    for (int idx = lane; idx < T; idx += BLK) ((float4*)x_s)[idx] = xb[idx];
    if (lane < H) { h0_s[lane] = 0.0f; h1_s[lane] = 0.0f; }

    const int rA = lane, rB = lane + 64;

    // ---- all weights in VGPRs, packed {rowA, rowB} for v_pk_fma_f32 ----
    v2f wh0[H];   // L1 W_hh0
    v2f wx0[D];   // L1 W_ih0
    v2f wi1[H];   // L2 W_ih1 (dotted with h0)
    v2f wh1[H];   // L2 W_hh1 (dotted with h1)
    v2f bias0, bias1;
    #pragma unroll
    for (int k = 0; k < H; ++k) wh0[k] = mk2(W_hh0[rA*H + k], W_hh0[rB*H + k]);
    #pragma unroll
    for (int k = 0; k < D; ++k) wx0[k] = mk2(W_ih0[rA*D + k], W_ih0[rB*D + k]);
    #pragma unroll
    for (int k = 0; k < H; ++k) wi1[k] = mk2(W_ih1[rA*H + k], W_ih1[rB*H + k]);
    #pragma unroll
    for (int k = 0; k < H; ++k) wh1[k] = mk2(W_hh1[rA*H + k], W_hh1[rB*H + k]);
    bias0 = mk2(b_ih0[rA] + b_hh0[rA], b_ih0[rB] + b_hh0[rB]);
    bias1 = mk2(b_ih1[rA] + b_hh1[rA], b_ih1[rB] + b_hh1[rB]);

    // rowB activation selector: lanes<32 -> tanh (g), lanes>=32 -> sigmoid (o)
    // tanh(z) = 2*sigmoid(2z) - 1
    const float s1  = (lane < H) ? 2.0f : 1.0f;
    const float off = (lane < H) ? 1.0f : 0.0f;
    const float wout = (lane < H) ? W_out[lane] : 0.0f;

    float c0 = 0.0f, c1 = 0.0f;   // cell states, lanes<32
    float h1v = 0.0f;             // last h1 value (lanes<32)

    __syncthreads();  // single-wave: cheap; covers x_s/h init

    for (int t = 0; t < T; ++t) {
        // ---------------- layer 1, step t ----------------
        v2f acc0 = bias0, acc1 = mk2(0,0), acc2 = mk2(0,0), acc3 = mk2(0,0);
        {
            const float4* h0p = (const float4*)h0_s;
            #pragma unroll
            for (int kk = 0; kk < H/4; ++kk) {
                float4 h4 = h0p[kk];
                acc0 += h4.x * wh0[4*kk+0];
                acc1 += h4.y * wh0[4*kk+1];
                acc2 += h4.z * wh0[4*kk+2];
                acc3 += h4.w * wh0[4*kk+3];
            }
            float4 xv = ((const float4*)x_s)[t];
            acc0 += xv.x * wx0[0];
            acc1 += xv.y * wx0[1];
            acc2 += xv.z * wx0[2];
            acc3 += xv.w * wx0[3];
        }
        v2f g2 = (acc0 + acc1) + (acc2 + acc3);
        float a0 = __builtin_amdgcn_rcpf(1.0f + __expf(-g2.x));           // i | f
        float sg = __builtin_amdgcn_rcpf(1.0f + __expf(-g2.y * s1));
        float a1 = fmaf(sg, s1, -off);                                    // g | o
        float f_ = __shfl_xor(a0, 32);
        float o_ = __shfl_xor(a1, 32);
        if (lane < H) {
            c0 = fmaf(f_, c0, a0 * a1);
            float th = fmaf(__builtin_amdgcn_rcpf(1.0f + __expf(-2.0f * c0)), 2.0f, -1.0f);
            h0_s[lane] = o_ * th;
        }

        // ---------------- layer 2, step t ----------------
        // h1 part first (reads OLD h1_s, independent of the h0 write above,
        // so the h0 write->read latency hides under these 32 pk_fma)
        acc0 = bias1; acc1 = mk2(0,0); acc2 = mk2(0,0); acc3 = mk2(0,0);
        {
            const float4* h1p = (const float4*)h1_s;
            #pragma unroll
            for (int kk = 0; kk < H/4; ++kk) {
                float4 h4 = h1p[kk];
                acc0 += h4.x * wh1[4*kk+0];
                acc1 += h4.y * wh1[4*kk+1];
                acc2 += h4.z * wh1[4*kk+2];
                acc3 += h4.w * wh1[4*kk+3];
            }
            const float4* h0p = (const float4*)h0_s;  // NEW h0 (just written)
            #pragma unroll
            for (int kk = 0; kk < H/4; ++kk) {
                float4 h4 = h0p[kk];
                acc0 += h4.x * wi1[4*kk+0];
                acc1 += h4.y * wi1[4*kk+1];
                acc2 += h4.z * wi1[4*kk+2];
                acc3 += h4.w * wi1[4*kk+3];
            }
        }
        g2 = (acc0 + acc1) + (acc2 + acc3);
        a0 = __builtin_amdgcn_rcpf(1.0f + __expf(-g2.x));
        sg = __builtin_amdgcn_rcpf(1.0f + __expf(-g2.y * s1));
        a1 = fmaf(sg, s1, -off);
        f_ = __shfl_xor(a0, 32);
        o_ = __shfl_xor(a1, 32);
        if (lane < H) {
            c1 = fmaf(f_, c1, a0 * a1);
            float th = fmaf(__builtin_amdgcn_rcpf(1.0f + __expf(-2.0f * c1)), 2.0f, -1.0f);
            h1v = o_ * th;
            h1_s[lane] = h1v;
        }
    }

    // ---- output head: out[b] = b_out + W_out . h1(T-1), wave reduction ----
    float p = (lane < H) ? wout * h1v : 0.0f;
    #pragma unroll
    for (int d = 1; d < 32; d <<= 1) p += __shfl_xor(p, d);
    // lanes 0..31 now each hold the full sum over lanes<32
    if (lane == 0) out[b] = p + b_out[0];
}

extern "C" void kernel_launch(void* const* d_in, const int* in_sizes, int n_in,
                              void* d_out, int out_size, void* d_ws, size_t ws_size,
                              hipStream_t stream) {
    const float* x     = (const float*)d_in[0];
    const float* W_ih0 = (const float*)d_in[1];
    const float* W_hh0 = (const float*)d_in[2];
    const float* b_ih0 = (const float*)d_in[3];
    const float* b_hh0 = (const float*)d_in[4];
    const float* W_ih1 = (const float*)d_in[5];
    const float* W_hh1 = (const float*)d_in[6];
    const float* b_ih1 = (const float*)d_in[7];
    const float* b_hh1 = (const float*)d_in[8];
    const float* W_out = (const float*)d_in[9];
    const float* b_out = (const float*)d_in[10];
    float* out = (float*)d_out;

    const int B = out_size;   // 4096
    lstm_fused<<<B, BLK, 0, stream>>>(x, W_ih0, W_hh0, b_ih0, b_hh0,
                                      W_ih1, W_hh1, b_ih1, b_hh1,
                                      W_out, b_out, out);
}

// Round 4
// 1038.094 us; speedup vs baseline: 1.3595x; 1.1477x over previous
//
#include <hip/hip_runtime.h>
#include <cmath>

// x [B=4096][T=512][D=4], H=32, 4H=128 gate rows per layer.
constexpr int T   = 512;
constexpr int D   = 4;
constexpr int H   = 32;
constexpr int BLK = 64;   // ONE wave per batch element; both layers in-wave; no barriers

typedef float v2f __attribute__((ext_vector_type(2)));

static __device__ __forceinline__ v2f mk2(float a, float b) {
    v2f r; r.x = a; r.y = b; return r;
}

// broadcast lane k of a float VGPR to all lanes as an SGPR (wave-uniform)
static __device__ __forceinline__ float rlane(float v, int k) {
    return __int_as_float(__builtin_amdgcn_readlane(__float_as_int(v), k));
}

static __device__ __forceinline__ float sigm(float z) {
    return __builtin_amdgcn_rcpf(1.0f + __expf(-z));
}

// Lane l owns gate rows (l, l+64) of BOTH layers:
//   l<32 : rowA = i-gate[l],    rowB = g-gate[l]   (tanh on rowB)
//   l>=32: rowA = f-gate[l-32], rowB = o-gate[l-32]
// f,o reach lanes<32 via __shfl_xor(32). Hidden states h0,h1 live in VGPRs
// (lanes<32) and are broadcast via v_readlane->SGPR into the pk_fma dots —
// ZERO LDS traffic for h (the DS pipe was the R3 bottleneck). Lanes>=32
// compute junk c/h that is never read (no predication needed).
__global__ __launch_bounds__(BLK, 2) void lstm_fused(
    const float* __restrict__ x,
    const float* __restrict__ W_ih0, const float* __restrict__ W_hh0,
    const float* __restrict__ b_ih0, const float* __restrict__ b_hh0,
    const float* __restrict__ W_ih1, const float* __restrict__ W_hh1,
    const float* __restrict__ b_ih1, const float* __restrict__ b_hh1,
    const float* __restrict__ W_out, const float* __restrict__ b_out,
    float* __restrict__ out)
{
    __shared__ __align__(16) float x_s[T * D];   // 8 KB

    const int lane = threadIdx.x;   // 0..63
    const int b    = blockIdx.x;

    // preload x[b] (contiguous, coalesced float4: 8 per lane)
    const float4* xb = (const float4*)(x + (size_t)b * (T * D));
    #pragma unroll
    for (int idx = lane; idx < T; idx += BLK) ((float4*)x_s)[idx] = xb[idx];

    const int rA = lane, rB = lane + 64;

    // ---- all weights in VGPRs, packed {rowA, rowB} for v_pk_fma_f32 ----
    v2f wh0[H];   // L1 W_hh0            (dot with h0 broadcasts)
    v2f wx0[D];   // L1 W_ih0            (dot with x[t])
    v2f wi1[H];   // L2 W_ih1            (dot with h0 broadcasts)
    v2f wh1[H];   // L2 W_hh1            (dot with h1 broadcasts)
    v2f bias0, bias1;
    #pragma unroll
    for (int k = 0; k < H; ++k) wh0[k] = mk2(W_hh0[rA*H + k], W_hh0[rB*H + k]);
    #pragma unroll
    for (int k = 0; k < D; ++k) wx0[k] = mk2(W_ih0[rA*D + k], W_ih0[rB*D + k]);
    #pragma unroll
    for (int k = 0; k < H; ++k) wi1[k] = mk2(W_ih1[rA*H + k], W_ih1[rB*H + k]);
    #pragma unroll
    for (int k = 0; k < H; ++k) wh1[k] = mk2(W_hh1[rA*H + k], W_hh1[rB*H + k]);
    bias0 = mk2(b_ih0[rA] + b_hh0[rA], b_ih0[rB] + b_hh0[rB]);
    bias1 = mk2(b_ih1[rA] + b_hh1[rA], b_ih1[rB] + b_hh1[rB]);

    // rowB activation selector: lanes<32 -> tanh (g), lanes>=32 -> sigmoid (o)
    const float s1  = (lane < H) ? 2.0f : 1.0f;
    const float off = (lane < H) ? 1.0f : 0.0f;
    const float wout = W_out[lane & (H - 1)];

    float c0 = 0.0f, c1 = 0.0f;     // cell states (valid in lanes<32)
    float hv0 = 0.0f, hv1 = 0.0f;   // hidden states (valid in lanes<32)

    __syncthreads();  // single wave: covers x_s init

    for (int t = 0; t < T; ++t) {
        // ---------------- layer 1, step t ----------------
        v2f acc0 = bias0, acc1 = mk2(0,0), acc2 = mk2(0,0), acc3 = mk2(0,0);
        #pragma unroll
        for (int k = 0; k < H; k += 4) {
            float h0a = rlane(hv0, k    );
            float h0b = rlane(hv0, k + 1);
            float h0c = rlane(hv0, k + 2);
            float h0d = rlane(hv0, k + 3);
            acc0 += wh0[k    ] * h0a;
            acc1 += wh0[k + 1] * h0b;
            acc2 += wh0[k + 2] * h0c;
            acc3 += wh0[k + 3] * h0d;
        }
        {
            float4 xv = ((const float4*)x_s)[t];
            acc0 += wx0[0] * xv.x;
            acc1 += wx0[1] * xv.y;
            acc2 += wx0[2] * xv.z;
            acc3 += wx0[3] * xv.w;
        }
        v2f g2 = (acc0 + acc1) + (acc2 + acc3);
        float a0 = sigm(g2.x);                     // i | f
        float sg = sigm(g2.y * s1);
        float a1 = fmaf(sg, s1, -off);             // g | o
        float f_ = __shfl_xor(a0, 32);
        float o_ = __shfl_xor(a1, 32);
        c0  = fmaf(f_, c0, a0 * a1);               // junk in lanes>=32, never read
        hv0 = o_ * fmaf(sigm(2.0f * c0), 2.0f, -1.0f);

        // ---------------- layer 2, step t ----------------
        // old-h1 dot first (independent of the hv0 chain above -> hides it)
        acc0 = bias1; acc1 = mk2(0,0); acc2 = mk2(0,0); acc3 = mk2(0,0);
        #pragma unroll
        for (int k = 0; k < H; k += 4) {
            float h1a = rlane(hv1, k    );
            float h1b = rlane(hv1, k + 1);
            float h1c = rlane(hv1, k + 2);
            float h1d = rlane(hv1, k + 3);
            acc0 += wh1[k    ] * h1a;
            acc1 += wh1[k + 1] * h1b;
            acc2 += wh1[k + 2] * h1c;
            acc3 += wh1[k + 3] * h1d;
        }
        #pragma unroll
        for (int k = 0; k < H; k += 4) {           // NEW h0 broadcasts
            float h0a = rlane(hv0, k    );
            float h0b = rlane(hv0, k + 1);
            float h0c = rlane(hv0, k + 2);
            float h0d = rlane(hv0, k + 3);
            acc0 += wi1[k    ] * h0a;
            acc1 += wi1[k + 1] * h0b;
            acc2 += wi1[k + 2] * h0c;
            acc3 += wi1[k + 3] * h0d;
        }
        g2 = (acc0 + acc1) + (acc2 + acc3);
        a0 = sigm(g2.x);
        sg = sigm(g2.y * s1);
        a1 = fmaf(sg, s1, -off);
        f_ = __shfl_xor(a0, 32);
        o_ = __shfl_xor(a1, 32);
        c1  = fmaf(f_, c1, a0 * a1);
        hv1 = o_ * fmaf(sigm(2.0f * c1), 2.0f, -1.0f);
    }

    // ---- output head: out[b] = b_out + W_out . h1(T-1), wave reduction ----
    float p = (lane < H) ? wout * hv1 : 0.0f;
    #pragma unroll
    for (int d = 1; d < 32; d <<= 1) p += __shfl_xor(p, d);
    if (lane == 0) out[b] = p + b_out[0];
}

extern "C" void kernel_launch(void* const* d_in, const int* in_sizes, int n_in,
                              void* d_out, int out_size, void* d_ws, size_t ws_size,
                              hipStream_t stream) {
    const float* x     = (const float*)d_in[0];
    const float* W_ih0 = (const float*)d_in[1];
    const float* W_hh0 = (const float*)d_in[2];
    const float* b_ih0 = (const float*)d_in[3];
    const float* b_hh0 = (const float*)d_in[4];
    const float* W_ih1 = (const float*)d_in[5];
    const float* W_hh1 = (const float*)d_in[6];
    const float* b_ih1 = (const float*)d_in[7];
    const float* b_hh1 = (const float*)d_in[8];
    const float* W_out = (const float*)d_in[9];
    const float* b_out = (const float*)d_in[10];
    float* out = (float*)d_out;

    const int B = out_size;   // 4096
    lstm_fused<<<B, BLK, 0, stream>>>(x, W_ih0, W_hh0, b_ih0, b_hh0,
                                      W_ih1, W_hh1, b_ih1, b_hh1,
                                      W_out, b_out, out);
}